// Round 7
// baseline (227.260 us; speedup 1.0000x reference)
//
#include <hip/hip_runtime.h>
#include <hip/hip_bf16.h>

typedef unsigned short u16;
typedef unsigned int u32;
typedef __attribute__((ext_vector_type(4))) float f32x4;
typedef __attribute__((ext_vector_type(8))) __bf16 bf16x8;

#define B_   2
#define T_   2048
#define DM   2048
#define NH   16
#define NKV  4
#define HD   128

__device__ __forceinline__ u16 f2bf(float f){
    u32 u = __builtin_bit_cast(u32, f);
    u += 0x7FFFu + ((u >> 16) & 1u);
    return (u16)(u >> 16);
}

__device__ __forceinline__ float ex2(float x){
    float r; asm("v_exp_f32 %0, %1" : "=v"(r) : "v"(x)); return r;
}

__device__ __forceinline__ void gld_lds16(const void* g, void* l){
    __builtin_amdgcn_global_load_lds(
        (const __attribute__((address_space(1))) void*)g,
        (__attribute__((address_space(3))) void*)l, 16, 0, 0);
}

// ---------------- elementwise cast (f32 -> bf16), vectorized ----------------
__global__ void cast_v4(const float* __restrict__ in, u16* __restrict__ out){
    int i = blockIdx.x * 256 + threadIdx.x;
    float4 v = ((const float4*)in)[i];
    ushort4 o;
    o.x = f2bf(v.x); o.y = f2bf(v.y); o.z = f2bf(v.z); o.w = f2bf(v.w);
    ((ushort4*)out)[i] = o;
}

// ---------------- all W (K=2048, N) f32 -> Wt (N, K) bf16, one launch ----------------
// Q/K sections get the rope-pair column permutation: d' = 2*(d&63) + (d>>6)
__global__ void transAll(const float* __restrict__ Wq, const float* __restrict__ Wk,
                         const float* __restrict__ Wv, const float* __restrict__ Wo,
                         u16* __restrict__ Wqkv, u16* __restrict__ Wot){
    __shared__ float tile[32][33];
    int bx = blockIdx.x;
    const float* W; u16* Out; int N; int nb; int perm;
    if (bx < 64)      { W = Wq; Out = Wqkv;                  N = 2048; nb = bx;      perm = 1; }
    else if (bx < 80) { W = Wk; Out = Wqkv + 2048ull * 2048; N = 512;  nb = bx - 64; perm = 1; }
    else if (bx < 96) { W = Wv; Out = Wqkv + 2560ull * 2048; N = 512;  nb = bx - 80; perm = 0; }
    else              { W = Wo; Out = Wot;                   N = 2048; nb = bx - 96; perm = 0; }
    int n0 = nb * 32, k0 = blockIdx.y * 32;
    int tx = threadIdx.x, ty = threadIdx.y;
#pragma unroll
    for (int i = 0; i < 4; i++)
        tile[ty + i * 8][tx] = W[(size_t)(k0 + ty + i * 8) * N + n0 + tx];
    __syncthreads();
#pragma unroll
    for (int i = 0; i < 4; i++){
        int n = n0 + ty + i * 8;
        int np = perm ? ((n & ~127) | ((n & 63) << 1) | ((n >> 6) & 1)) : n;
        Out[(size_t)np * 2048 + k0 + tx] = f2bf(tile[tx][ty + i * 8]);
    }
}

// ---------------- RoPE cos/sin table: (t, i) -> float2 ----------------
__global__ void rope_tab(float2* __restrict__ tab){
    int idx = blockIdx.x * 256 + threadIdx.x;   // 2048*64
    int i = idx & 63, t = idx >> 6;
    float ang = (float)t * exp2f((float)i * (-13.287712379549449f / 64.0f));
    float sv, cv;
    __sincosf(ang, &sv, &cv);
    tab[idx] = make_float2(cv, sv);
}

// ================= 128x256 pipelined GEMM (T2+T3+T4+T5) =================
// C = A(4096,2048) * Bt(N,2048)^T. 512 threads, 8 waves (2M x 4N), BK=64.
// Tile 128x256 -> grids: QKV 32x12=384, Wo 32x8=256 (full machine for Wo).
// LDS 96 KB: As[2][128x64] 32K, Bs[2][256x64] 64K. XOR-swizzle: k-chunk ^= row&7
// (pre-permuted global source kcx; swizzled ds_read). Regions: A (16KB),
// B.q0 / B.q1 (16KB each = rows {wn*64+q*32..+31}).
// Phase rhythm (4 phases / 2 K-tiles, 16 MFMA/wave/phase):
//   ph0: rdA(b0) rdB0(b0) | stage b1.Bq1(T1)          | BAR lgkm MFMA BAR
//   ph1: rdB1(b0)         | stage b0.A(T2) b0.Bq0(T2) | BAR lgkm MFMA vm(4) BAR
//   ph2: rdA(b1) rdB0(b1) | stage b0.Bq1(T2)          | BAR lgkm MFMA BAR
//   ph3: rdB1(b1)         | stage b1.A(T3) b1.Bq0(T3) | BAR lgkm MFMA vm(4) BAR
// Liveness: A,Bq0 die after ph0 reads; Bq1 after ph1 (per buffer). Every stage
// targets a dead region after a barrier. vmcnt invariant: 10 outstanding -> 4.
#define BARR() __builtin_amdgcn_s_barrier()
#define LGKM0() { asm volatile("s_waitcnt lgkmcnt(0)" ::: "memory"); __builtin_amdgcn_sched_barrier(0); }
#define VM4() asm volatile("s_waitcnt vmcnt(4)" ::: "memory")

#define READ_A(BUF) { \
    const char* ab = (const char*)&As[BUF][0]; \
    _Pragma("unroll") for (int mi = 0; mi < 4; mi++){ \
        int ra = wm*64 + mi*16 + lx; \
        _Pragma("unroll") for (int ks = 0; ks < 2; ks++) \
            a_[mi][ks] = *(const bf16x8*)(ab + ra*128 + (((ks*4+tg)*16) ^ ((lx&7)<<4))); \
    } }
#define READ_B(QB, BUF) { \
    const char* bb = (const char*)&Bs[BUF][0] + (QB)*16384; \
    _Pragma("unroll") for (int n = 0; n < 2; n++){ \
        int rb = wn*32 + n*16 + lx; \
        _Pragma("unroll") for (int ks = 0; ks < 2; ks++) \
            b_[n][ks] = *(const bf16x8*)(bb + rb*128 + (((ks*4+tg)*16) ^ ((lx&7)<<4))); \
    } }
#define MFMA_P(QB) { \
    __builtin_amdgcn_s_setprio(1); \
    _Pragma("unroll") for (int mi = 0; mi < 4; mi++) \
    _Pragma("unroll") for (int n = 0; n < 2; n++) \
    _Pragma("unroll") for (int ks = 0; ks < 2; ks++) \
        acc[mi][(QB)*2+n] = __builtin_amdgcn_mfma_f32_16x16x32_bf16( \
            a_[mi][ks], b_[n][ks], acc[mi][(QB)*2+n], 0, 0, 0); \
    __builtin_amdgcn_s_setprio(0); }

template<int MODE>
__global__ __launch_bounds__(512, 2) void gemm128(const u16* __restrict__ A, const u16* __restrict__ Bt,
                                                  void* __restrict__ O0, u16* __restrict__ Ktl,
                                                  u16* __restrict__ Vtl, const float2* __restrict__ tab,
                                                  int NBX){
    __shared__ __attribute__((aligned(16))) u16 As[2][8192];    // 128 x 64 per buf
    __shared__ __attribute__((aligned(16))) u16 Bs[2][16384];   // 256 x 64 per buf
    const int tid = threadIdx.x;
    const int lane = tid & 63, w = tid >> 6;
    const int wm = w >> 2, wn = w & 3;
    const int tg = lane >> 4, lx = lane & 15;
    // XCD-aware bijective swizzle (grid % 8 == 0)
    int q8 = (int)gridDim.x >> 3;
    int swz = ((int)blockIdx.x & 7) * q8 + ((int)blockIdx.x >> 3);
    const int bx = swz % NBX, by = swz / NBX;
    const int m0 = by * 128, n0 = bx * 256;
    const int K = 2048;
    const int kcx = (lane & 7) ^ ((lane >> 3) & 7);

    f32x4 acc[4][4];
    const f32x4 Z = {0.f, 0.f, 0.f, 0.f};
#pragma unroll
    for (int i = 0; i < 4; i++)
#pragma unroll
        for (int j = 0; j < 4; j++) acc[i][j] = Z;
    bf16x8 a_[4][2], b_[2][2];

    // A region: 16 KB, rows 0..127 of the tile. 2 loads/thread.
    auto stA = [&](int buf, int kt){
#pragma unroll
        for (int l = 0; l < 2; l++){
            int s = w * 2 + l;                       // 0..15
            gld_lds16(A + (size_t)(m0 + s*8 + (lane>>3)) * K + kt*64 + kcx*8,
                      &As[buf][s*512 + lane*8]);
        }
    };
    // B region q: 16 KB, rows {wn*64 + q*32 .. +31} for all 4 wn-stripes.
    auto stB = [&](int buf, int q, int kt){
#pragma unroll
        for (int l = 0; l < 2; l++){
            int s = w * 2 + l;
            int rr = s*8 + (lane>>3);                // 0..127
            gld_lds16(Bt + (size_t)(n0 + (rr>>5)*64 + q*32 + (rr&31)) * K + kt*64 + kcx*8,
                      &Bs[buf][q*8192 + s*512 + lane*8]);
        }
    };

    // prologue: buf0 <- T0 (full), buf1 <- T1 (A, Bq0). 10 loads out.
    stA(0, 0); stB(0, 0, 0); stB(0, 1, 0);
    stA(1, 1); stB(1, 0, 1);
    VM4(); BARR();

#pragma unroll 1
    for (int it = 0; it < 16; it++){
        const int T1 = 2*it + 1;
        const int T2 = (2*it + 2 < 32) ? 2*it + 2 : 31;
        const int T3 = (2*it + 3 < 32) ? 2*it + 3 : 31;
        // ph0 — buf0, QB0
        READ_A(0); READ_B(0, 0);
        stB(1, 1, T1);
        BARR(); LGKM0(); MFMA_P(0); BARR();
        // ph1 — buf0, QB1
        READ_B(1, 0);
        stA(0, T2); stB(0, 0, T2);
        BARR(); LGKM0(); MFMA_P(1); VM4(); BARR();
        // ph2 — buf1, QB0
        READ_A(1); READ_B(0, 1);
        stB(0, 1, T2);
        BARR(); LGKM0(); MFMA_P(0); BARR();
        // ph3 — buf1, QB1
        READ_B(1, 1);
        stA(1, T3); stB(1, 0, T3);
        BARR(); LGKM0(); MFMA_P(1); VM4(); BARR();
    }

    // ---------------- epilogue ----------------
    if constexpr (MODE == 0){
        float* C = (float*)O0;
#pragma unroll
        for (int mi = 0; mi < 4; mi++)
#pragma unroll
            for (int ni = 0; ni < 4; ni++){
                int r0 = m0 + wm*64 + mi*16 + tg*4;
                int c  = n0 + wn*64 + ni*16 + lx;
#pragma unroll
                for (int j = 0; j < 4; j++)
                    C[(size_t)(r0 + j) * 2048 + c] = acc[mi][ni][j];
            }
    } else {
        u16* Qp = (u16*)O0;
        if (bx < 8){
            // Q + rope, pre-scaled by softmax-scale * log2(e) (attn works in exp2 domain)
            const float QS = 0.08838834764831845f * 1.4426950408889634f;
#pragma unroll
            for (int mi = 0; mi < 4; mi++)
#pragma unroll
                for (int ni = 0; ni < 4; ni++){
                    int r0 = m0 + wm*64 + mi*16 + tg*4;
                    int c  = n0 + wn*64 + ni*16 + lx;
                    int ii = (c & 127) >> 1;
#pragma unroll
                    for (int j = 0; j < 4; j++){
                        float v = acc[mi][ni][j];
                        float p = __shfl_xor(v, 1);
                        int t = (r0 + j) & 2047;
                        float2 cs = tab[t * 64 + ii];
                        float o = ((lx & 1) ? (v * cs.x + p * cs.y) : (v * cs.x - p * cs.y)) * QS;
                        Qp[(size_t)(r0 + j) * 2048 + c] = f2bf(o);
                    }
                }
        } else if (bx < 10){
#pragma unroll
            for (int mi = 0; mi < 4; mi++)
#pragma unroll
                for (int ni = 0; ni < 4; ni++){
                    int r0 = m0 + wm*64 + mi*16 + tg*4;
                    int c  = n0 + wn*64 + ni*16 + lx;
                    int hk = (c >> 7) & 3;
                    int dd = c & 127;
                    int ii = dd >> 1;
#pragma unroll
                    for (int j = 0; j < 4; j++){
                        int r = r0 + j;
                        int bb2 = r >> 11, tt = r & 2047;
                        float v = acc[mi][ni][j];
                        float p = __shfl_xor(v, 1);
                        float2 cs = tab[tt * 64 + ii];
                        float o = (lx & 1) ? (v * cs.x + p * cs.y) : (v * cs.x - p * cs.y);
                        size_t tb = ((size_t)(bb2 * 4 + hk) * 32 + (tt >> 6)) * 8192;
                        u32 byte = (u32)((tt & 63) * 256) + (((u32)(2 * dd)) ^ ((u32)((tt & 7) << 4)));
                        Ktl[tb + byte / 2] = f2bf(o);
                    }
                }
        } else {
            // V: tiled transposed, sigma-permuted rows (sig(s) = (s&15)*4 + (s>>4)&3),
            // swizzled byte^=(d&7)<<4 — matches attn's P sigma-column layout.
#pragma unroll
            for (int mi = 0; mi < 4; mi++){
                int r0 = m0 + wm*64 + mi*16 + tg*4;
                int bb2 = r0 >> 11, ss = r0 & 2047;
                int sb = ss & 63;
#pragma unroll
                for (int ni = 0; ni < 4; ni++){
                    int c  = n0 + wn*64 + ni*16 + lx;
                    int hk = (c >> 7) & 3;
                    int d  = c & 127;
                    size_t tb = ((size_t)(bb2 * 4 + hk) * 32 + (ss >> 6)) * 8192;
                    u32 swzd = (u32)((d & 7) << 4);
#pragma unroll
                    for (int j = 0; j < 4; j++){
                        int s = sb + j;
                        int sig = ((s & 15) << 2) | ((s >> 4) & 3);
                        u32 byte = (u32)(d * 128) + (((u32)(2 * sig)) ^ swzd);
                        Vtl[tb + byte / 2] = f2bf(acc[mi][ni][j]);
                    }
                }
            }
        }
    }
}

// ---------------- causal GQA flash attention ----------------
// Q: plain (b*T+t, h*128+d) bf16, PRE-SCALED by scale*log2e (exp2 domain)
// Kt: [b][hkv][t32][s64][d128] swizzled (byte^=(s&7)<<4)
// Vt: [b][hkv][t32][d128][sig64] sigma-permuted, swizzled (byte^=(d&7)<<4)
__global__ __launch_bounds__(256) void attn5(const u16* __restrict__ Q, const u16* __restrict__ Kt,
                                             const u16* __restrict__ Vt, u16* __restrict__ Y){
    __shared__ __attribute__((aligned(16))) u16 Ks[2][64 * 128];
    __shared__ __attribute__((aligned(16))) u16 Vs[2][64 * 128];
    __shared__ __attribute__((aligned(16))) u16 Pl[4][16 * 64];
    const int lane = threadIdx.x & 63, w = threadIdx.x >> 6;
    const int jb = blockIdx.x, h = blockIdx.y, b = blockIdx.z;
    const int hkv = h >> 2;
    const size_t kvBase = ((size_t)(b * NKV + hkv) * 32) * 8192;
    const f32x4 Z = {0.f, 0.f, 0.f, 0.f};
    const int tg = lane >> 4, lx = lane & 15;

    auto STAGE = [&](int buf, int it){
        const u16* kg = Kt + kvBase + (size_t)it * 8192;
        const u16* vg = Vt + kvBase + (size_t)it * 8192;
#pragma unroll
        for (int i = 0; i < 4; i++){
            int is = w * 4 + i;
            gld_lds16(kg + is * 512 + lane * 8, &Ks[buf][is * 512]);
            gld_lds16(vg + is * 512 + lane * 8, &Vs[buf][is * 512]);
        }
    };

#pragma unroll 1
    for (int pass = 0; pass < 2; pass++){
        const int qt = pass == 0 ? jb : 31 - jb;
        const int q0 = qt * 64;
        const int qrow = q0 + w * 16 + lx;
        bf16x8 qfr[4];
#pragma unroll
        for (int kk = 0; kk < 4; kk++)
            qfr[kk] = *(const bf16x8*)(Q + (size_t)(b * T_ + qrow) * DM + h * HD + kk * 32 + tg * 8);
        f32x4 accO[8];
#pragma unroll
        for (int i = 0; i < 8; i++) accO[i] = Z;
        float mr[4] = {-INFINITY, -INFINITY, -INFINITY, -INFINITY};
        float lp[4] = {0.f, 0.f, 0.f, 0.f};
        const int nIter = qt + 1;

        STAGE(0, 0);
        __syncthreads();
        int cur = 0;

#pragma unroll 1
        for (int it = 0; it < nIter; it++){
            if (it + 1 < nIter) STAGE(cur ^ 1, it + 1);
            // ---- QK^T: S[16q][64s] per wave (scores already scaled, log2 domain) ----
            f32x4 sa[4];
#pragma unroll
            for (int c = 0; c < 4; c++) sa[c] = Z;
            __builtin_amdgcn_s_setprio(1);
#pragma unroll
            for (int c = 0; c < 4; c++){
                int s = c * 16 + lx;
                u32 swz = (u32)((s & 7) << 4);
                const char* kb = (const char*)&Ks[cur][0] + s * 256;
#pragma unroll
                for (int kk = 0; kk < 4; kk++){
                    bf16x8 kf = *(const bf16x8*)(kb + (((u32)(kk * 64 + tg * 16)) ^ swz));
                    sa[c] = __builtin_amdgcn_mfma_f32_16x16x32_bf16(qfr[kk], kf, sa[c], 0, 0, 0);
                }
            }
            __builtin_amdgcn_s_setprio(0);
            // ---- mask + per-lane local max ----
            const bool diag = (it == nIter - 1);
            float tl[4];
#pragma unroll
            for (int j = 0; j < 4; j++){
                float a0 = sa[0][j], a1 = sa[1][j], a2 = sa[2][j], a3 = sa[3][j];
                if (diag){
                    int qloc = w * 16 + tg * 4 + j;
                    if (lx      > qloc) a0 = -INFINITY;
                    if (lx + 16 > qloc) a1 = -INFINITY;
                    if (lx + 32 > qloc) a2 = -INFINITY;
                    if (lx + 48 > qloc) a3 = -INFINITY;
                }
                sa[0][j] = a0; sa[1][j] = a1; sa[2][j] = a2; sa[3][j] = a3;
                tl[j] = fmaxf(fmaxf(a0, a1), fmaxf(a2, a3));
            }
            // ---- shfl-free defer check (T13); full reduce only on growth ----
            int lok = (tl[0] <= mr[0] + 8.f) && (tl[1] <= mr[1] + 8.f) &&
                      (tl[2] <= mr[2] + 8.f) && (tl[3] <= mr[3] + 8.f);
            if (!__all(lok)){
                float corr[4];
#pragma unroll
                for (int j = 0; j < 4; j++){
                    float t = tl[j];
                    t = fmaxf(t, __shfl_xor(t, 1));
                    t = fmaxf(t, __shfl_xor(t, 2));
                    t = fmaxf(t, __shfl_xor(t, 4));
                    t = fmaxf(t, __shfl_xor(t, 8));
                    float mn = fmaxf(mr[j], t);
                    corr[j] = ex2(mr[j] - mn);
                    mr[j] = mn;
                    lp[j] *= corr[j];
                }
#pragma unroll
                for (int dt = 0; dt < 8; dt++){
                    f32x4 t = accO[dt];
                    t[0] *= corr[0]; t[1] *= corr[1]; t[2] *= corr[2]; t[3] *= corr[3];
                    accO[dt] = t;
                }
            }
            // ---- P = exp2(S - m); pack pairs (cvt_pk) and one ds_write_b64 per row ----
#pragma unroll
            for (int j = 0; j < 4; j++){
                float mn = mr[j];
                float p0 = ex2(sa[0][j] - mn), p1 = ex2(sa[1][j] - mn);
                float p2 = ex2(sa[2][j] - mn), p3 = ex2(sa[3][j] - mn);
                lp[j] += p0 + p1 + p2 + p3;
                int rr = tg * 4 + j;
                u32 woff = (u32)(rr * 128) + (((u32)(lx * 8)) ^ ((u32)((rr & 7) << 4)));
                u32 r01, r23;
                asm("v_cvt_pk_bf16_f32 %0, %1, %2" : "=v"(r01) : "v"(p0), "v"(p1));
                asm("v_cvt_pk_bf16_f32 %0, %1, %2" : "=v"(r23) : "v"(p2), "v"(p3));
                uint2 pk2 = make_uint2(r01, r23);
                *(uint2*)((char*)&Pl[w][0] + woff) = pk2;
            }
            // ---- read P as A-fragments (sigma-column space) ----
            bf16x8 pf[2];
            {
                char* pb = (char*)&Pl[w][0] + lx * 128;
                u32 swz = (u32)((lx & 7) << 4);
                pf[0] = *(const bf16x8*)(pb + (((u32)(tg * 16))      ^ swz));
                pf[1] = *(const bf16x8*)(pb + (((u32)(tg * 16 + 64)) ^ swz));
            }
            // ---- PV (V rows sigma-permuted to match) ----
            __builtin_amdgcn_s_setprio(1);
#pragma unroll
            for (int dt = 0; dt < 8; dt++){
                int d = dt * 16 + lx;
                u32 swz = (u32)((d & 7) << 4);
                const char* vb = (const char*)&Vs[cur][0] + d * 128;
                bf16x8 vf0 = *(const bf16x8*)(vb + (((u32)(tg * 16))      ^ swz));
                bf16x8 vf1 = *(const bf16x8*)(vb + (((u32)(tg * 16 + 64)) ^ swz));
                accO[dt] = __builtin_amdgcn_mfma_f32_16x16x32_bf16(pf[0], vf0, accO[dt], 0, 0, 0);
                accO[dt] = __builtin_amdgcn_mfma_f32_16x16x32_bf16(pf[1], vf1, accO[dt], 0, 0, 0);
            }
            __builtin_amdgcn_s_setprio(0);
            __syncthreads();
            cur ^= 1;
        }
        // ---- epilogue: reduce deferred sums, normalize, store ----
        float inv[4];
#pragma unroll
        for (int j = 0; j < 4; j++){
            float s = lp[j];
            s += __shfl_xor(s, 1);
            s += __shfl_xor(s, 2);
            s += __shfl_xor(s, 4);
            s += __shfl_xor(s, 8);
            inv[j] = 1.0f / s;
        }
#pragma unroll
        for (int dt = 0; dt < 8; dt++)
#pragma unroll
            for (int j = 0; j < 4; j++){
                int qr = q0 + w * 16 + tg * 4 + j;
                int d = dt * 16 + lx;
                Y[(size_t)(b * T_ + qr) * DM + h * HD + d] = f2bf(accO[dt][j] * inv[j]);
            }
    }
}

extern "C" void kernel_launch(void* const* d_in, const int* in_sizes, int n_in,
                              void* d_out, int out_size, void* d_ws, size_t ws_size,
                              hipStream_t stream){
    const float* x  = (const float*)d_in[0];
    const float* Wq = (const float*)d_in[1];
    const float* Wk = (const float*)d_in[2];
    const float* Wv = (const float*)d_in[3];
    const float* Wo = (const float*)d_in[4];

    char* ws = (char*)d_ws;
    size_t off = 0;
    auto alloc = [&](size_t bytes){ void* p = ws + off; off += (bytes + 255) & ~255ull; return p; };
    u16*    xb   = (u16*)alloc(4096ull * 2048 * 2);
    u16*    Wqkv = (u16*)alloc(3072ull * 2048 * 2);
    u16*    Wot  = (u16*)alloc(2048ull * 2048 * 2);
    u16*    qbb  = (u16*)alloc(4096ull * 2048 * 2);
    u16*    ktl  = (u16*)alloc(2ull * 4 * 32 * 8192 * 2);
    u16*    vtl  = (u16*)alloc(2ull * 4 * 32 * 8192 * 2);
    u16*    ybb  = (u16*)alloc(4096ull * 2048 * 2);
    float2* tab  = (float2*)alloc(2048ull * 64 * 8);

    cast_v4<<<8192, 256, 0, stream>>>(x, xb);
    transAll<<<dim3(160, 64), dim3(32, 8), 0, stream>>>(Wq, Wk, Wv, Wo, Wqkv, Wot);
    rope_tab<<<512, 256, 0, stream>>>(tab);

    gemm128<1><<<384, 512, 0, stream>>>(xb, Wqkv, qbb, ktl, vtl, tab, 12);

    attn5<<<dim3(16, 16, 2), 256, 0, stream>>>(qbb, ktl, vtl, ybb);

    gemm128<0><<<256, 512, 0, stream>>>(ybb, Wot, d_out, nullptr, nullptr, nullptr, 8);
}

// Round 8
// 218.412 us; speedup vs baseline: 1.0405x; 1.0405x over previous
//
#include <hip/hip_runtime.h>
#include <hip/hip_bf16.h>

typedef unsigned short u16;
typedef unsigned int u32;
typedef __attribute__((ext_vector_type(4))) float f32x4;
typedef __attribute__((ext_vector_type(8))) __bf16 bf16x8;

#define B_   2
#define T_   2048
#define DM   2048
#define NH   16
#define NKV  4
#define HD   128

__device__ __forceinline__ u16 f2bf(float f){
    u32 u = __builtin_bit_cast(u32, f);
    u += 0x7FFFu + ((u >> 16) & 1u);
    return (u16)(u >> 16);
}

__device__ __forceinline__ float ex2(float x){
    float r; asm("v_exp_f32 %0, %1" : "=v"(r) : "v"(x)); return r;
}

__device__ __forceinline__ void gld_lds16(const void* g, void* l){
    __builtin_amdgcn_global_load_lds(
        (const __attribute__((address_space(1))) void*)g,
        (__attribute__((address_space(3))) void*)l, 16, 0, 0);
}

// ---------------- fused prep: cast x, transpose weights, rope table ----------------
// grid: [0,8192) cast | [8192,18432) transW | [18432,18944) rope table
__global__ void prep(const float* __restrict__ x,
                     const float* __restrict__ Wq, const float* __restrict__ Wk,
                     const float* __restrict__ Wv, const float* __restrict__ Wo,
                     u16* __restrict__ xb, u16* __restrict__ Wqkv, u16* __restrict__ Wot,
                     float2* __restrict__ tab){
    __shared__ float tile[32][33];
    int bid = blockIdx.x, tid = threadIdx.x;
    if (bid < 8192){
        int i = bid * 256 + tid;
        float4 v = ((const float4*)x)[i];
        ushort4 o;
        o.x = f2bf(v.x); o.y = f2bf(v.y); o.z = f2bf(v.z); o.w = f2bf(v.w);
        ((ushort4*)xb)[i] = o;
    } else if (bid < 18432){
        int tb = bid - 8192;
        int bx = tb % 160, byy = tb / 160;
        const float* W; u16* Out; int N; int nb; int perm;
        if (bx < 64)      { W = Wq; Out = Wqkv;                  N = 2048; nb = bx;      perm = 1; }
        else if (bx < 80) { W = Wk; Out = Wqkv + 2048ull * 2048; N = 512;  nb = bx - 64; perm = 1; }
        else if (bx < 96) { W = Wv; Out = Wqkv + 2560ull * 2048; N = 512;  nb = bx - 80; perm = 0; }
        else              { W = Wo; Out = Wot;                   N = 2048; nb = bx - 96; perm = 0; }
        int n0 = nb * 32, k0 = byy * 32;
        int tx = tid & 31, ty = tid >> 5;
#pragma unroll
        for (int i = 0; i < 4; i++)
            tile[ty + i * 8][tx] = W[(size_t)(k0 + ty + i * 8) * N + n0 + tx];
        __syncthreads();
#pragma unroll
        for (int i = 0; i < 4; i++){
            int n = n0 + ty + i * 8;
            int np = perm ? ((n & ~127) | ((n & 63) << 1) | ((n >> 6) & 1)) : n;
            Out[(size_t)np * 2048 + k0 + tx] = f2bf(tile[tx][ty + i * 8]);
        }
    } else {
        int idx = (bid - 18432) * 256 + tid;   // 2048*64
        int i = idx & 63, t = idx >> 6;
        float ang = (float)t * exp2f((float)i * (-13.287712379549449f / 64.0f));
        float sv, cv;
        __sincosf(ang, &sv, &cv);
        tab[idx] = make_float2(cv, sv);
    }
}

// ================= 256x256 8-phase GEMM, read-ahead pipelined =================
// C = A(4096,K=2048) * Bt(N,2048)^T, 512 threads, 8 waves (2M x 4N), BK=64.
// LDS 128 KB: As/Bs[2 buf][2 half][128x64], XOR-swizzle via pre-permuted global
// source (kcx) + swizzled ds_read. Register sets A0/A1/B0/B1 are read ONE PHASE
// AHEAD of their MFMA use; compiler inserts counted lgkmcnt (no manual lgkm0,
// no sched_barrier) so LDS drain overlaps MFMA. Stages target dead regions:
//   ph1:A0b0(T+2) ph2:B0b0 ph3:A1b0+B1b0 ph5:A0b1(T+3) ph6:B0b1 ph7:B1b1+A1b1
// vmcnt(4) at ph2/ph6 end (before final BAR): retires all stages older than the
// last two phases' -> every region has VM+BAR between its stage and read-issue.
#define BARM() asm volatile("s_barrier" ::: "memory")
#define VM4()  asm volatile("s_waitcnt vmcnt(4)" ::: "memory")
#define VM8()  asm volatile("s_waitcnt vmcnt(8)" ::: "memory")

#define RD_A(SET, QA, BUF) { \
    const char* ab = (const char*)&As[BUF][wm][0]; \
    _Pragma("unroll") for (int i = 0; i < 4; i++){ \
        int rh = ((QA)*4 + i)*16 + lx; \
        _Pragma("unroll") for (int ks = 0; ks < 2; ks++) \
            SET[i][ks] = *(const bf16x8*)(ab + rh*128 + (((ks*4+tg)*16) ^ ((lx&7)<<4))); \
    } }
#define RD_B(SET, QB, BUF) { \
    const char* bb = (const char*)&Bs[BUF][wn>>1][0]; \
    _Pragma("unroll") for (int n = 0; n < 2; n++){ \
        int rbh = (wn&1)*64 + ((QB)*2+n)*16 + lx; \
        _Pragma("unroll") for (int ks = 0; ks < 2; ks++) \
            SET[n][ks] = *(const bf16x8*)(bb + rbh*128 + (((ks*4+tg)*16) ^ ((lx&7)<<4))); \
    } }
#define MM(ASET, QA, BSET, QB) { \
    __builtin_amdgcn_s_setprio(1); \
    _Pragma("unroll") for (int i = 0; i < 4; i++) \
    _Pragma("unroll") for (int n = 0; n < 2; n++) \
    _Pragma("unroll") for (int ks = 0; ks < 2; ks++) \
        acc[(QA)*4+i][(QB)*2+n] = __builtin_amdgcn_mfma_f32_16x16x32_bf16( \
            ASET[i][ks], BSET[n][ks], acc[(QA)*4+i][(QB)*2+n], 0, 0, 0); \
    __builtin_amdgcn_s_setprio(0); }

template<int MODE>
__global__ __launch_bounds__(512, 2) void gemm256(const u16* __restrict__ A, const u16* __restrict__ Bt,
                                                  void* __restrict__ O0, u16* __restrict__ Ktl,
                                                  u16* __restrict__ Vtl, const float2* __restrict__ tab,
                                                  int NBX){
    __shared__ __attribute__((aligned(16))) u16 As[2][2][8192];
    __shared__ __attribute__((aligned(16))) u16 Bs[2][2][8192];
    const int tid = threadIdx.x;
    const int lane = tid & 63, w = tid >> 6;
    const int wm = w >> 2, wn = w & 3;
    const int tg = lane >> 4, lx = lane & 15;
    int q8 = (int)gridDim.x >> 3;
    int swz = ((int)blockIdx.x & 7) * q8 + ((int)blockIdx.x >> 3);
    const int bx = swz % NBX, by = swz / NBX;
    const int m0 = by * 256, n0 = bx * 256;
    const int K = 2048;
    const int kcx = (lane & 7) ^ ((lane >> 3) & 7);

    f32x4 acc[8][4];
    const f32x4 Z = {0.f, 0.f, 0.f, 0.f};
#pragma unroll
    for (int i = 0; i < 8; i++)
#pragma unroll
        for (int j = 0; j < 4; j++) acc[i][j] = Z;
    bf16x8 A0[4][2], A1[4][2], B0[2][2], B1[2][2];

    auto stA = [&](int buf, int q, int kt){
        int mh = w >> 2;
        int s0 = (w & 3) * 2;
#pragma unroll
        for (int l = 0; l < 2; l++){
            int s = s0 + l;
            gld_lds16(A + (size_t)(m0 + mh*128 + q*64 + s*8 + (lane>>3)) * K + kt*64 + kcx*8,
                      &As[buf][mh][q*4096 + s*512 + lane*8]);
        }
    };
    auto stB = [&](int buf, int q, int kt){
        int bh = w >> 2;
        int hi = (w >> 1) & 1;
        int s0 = (w & 1) * 2;
#pragma unroll
        for (int l = 0; l < 2; l++){
            int s = s0 + l;
            gld_lds16(Bt + (size_t)(n0 + bh*128 + hi*64 + q*32 + s*8 + (lane>>3)) * K + kt*64 + kcx*8,
                      &Bs[buf][bh][hi*4096 + q*2048 + s*512 + lane*8]);
        }
    };

    // prologue: T0 full, T1 full; retire T0; preload ph0's registers
    stA(0, 0, 0); stB(0, 0, 0); stB(0, 1, 0); stA(0, 1, 0);
    stA(1, 0, 1); stB(1, 0, 1); stB(1, 1, 1); stA(1, 1, 1);
    VM8(); BARM();
    RD_A(A0, 0, 0); RD_B(B0, 0, 0);

#pragma unroll 1
    for (int it = 0; it < 16; it++){
        const int T2 = (2*it + 2 < 32) ? 2*it + 2 : 31;
        const int T3 = (2*it + 3 < 32) ? 2*it + 3 : 31;
        // ph0: q(0,0) buf0
        RD_B(B1, 1, 0);
        BARM(); MM(A0, 0, B0, 0); BARM();
        // ph1: q(0,1) buf0
        RD_A(A1, 1, 0);
        stA(0, 0, T2);
        BARM(); MM(A0, 0, B1, 1); BARM();
        // ph2: q(1,0) buf0
        stB(0, 0, T2);
        BARM(); MM(A1, 1, B0, 0); VM4(); BARM();
        // ph3: q(1,1) buf0; preload buf1 A0/B0
        RD_A(A0, 0, 1); RD_B(B0, 0, 1);
        stA(0, 1, T2); stB(0, 1, T2);
        BARM(); MM(A1, 1, B1, 1); BARM();
        // ph4: q(0,0) buf1
        RD_B(B1, 1, 1);
        BARM(); MM(A0, 0, B0, 0); BARM();
        // ph5: q(0,1) buf1
        RD_A(A1, 1, 1);
        stA(1, 0, T3);
        BARM(); MM(A0, 0, B1, 1); BARM();
        // ph6: q(1,0) buf1
        stB(1, 0, T3);
        BARM(); MM(A1, 1, B0, 0); VM4(); BARM();
        // ph7: q(1,1) buf1; preload next-iter buf0 A0/B0
        RD_A(A0, 0, 0); RD_B(B0, 0, 0);
        stB(1, 1, T3); stA(1, 1, T3);
        BARM(); MM(A1, 1, B1, 1); BARM();
    }

    // ---------------- epilogue ----------------
    if constexpr (MODE == 0){
        float* C = (float*)O0;
#pragma unroll
        for (int mi = 0; mi < 8; mi++)
#pragma unroll
            for (int ni = 0; ni < 4; ni++){
                int r0 = m0 + wm*128 + mi*16 + tg*4;
                int c  = n0 + wn*64 + ni*16 + lx;
#pragma unroll
                for (int j = 0; j < 4; j++)
                    C[(size_t)(r0 + j) * 2048 + c] = acc[mi][ni][j];
            }
    } else {
        u16* Qp = (u16*)O0;
        if (bx < 8){
            // Q + rope, pre-scaled by softmax-scale * log2(e) (attn works in exp2 domain)
            const float QS = 0.08838834764831845f * 1.4426950408889634f;
#pragma unroll
            for (int mi = 0; mi < 8; mi++)
#pragma unroll
                for (int ni = 0; ni < 4; ni++){
                    int r0 = m0 + wm*128 + mi*16 + tg*4;
                    int c  = n0 + wn*64 + ni*16 + lx;
                    int ii = (c & 127) >> 1;
#pragma unroll
                    for (int j = 0; j < 4; j++){
                        float v = acc[mi][ni][j];
                        float p = __shfl_xor(v, 1);
                        int t = (r0 + j) & 2047;
                        float2 cs = tab[t * 64 + ii];
                        float o = ((lx & 1) ? (v * cs.x + p * cs.y) : (v * cs.x - p * cs.y)) * QS;
                        Qp[(size_t)(r0 + j) * 2048 + c] = f2bf(o);
                    }
                }
        } else if (bx < 10){
#pragma unroll
            for (int mi = 0; mi < 8; mi++)
#pragma unroll
                for (int ni = 0; ni < 4; ni++){
                    int r0 = m0 + wm*128 + mi*16 + tg*4;
                    int c  = n0 + wn*64 + ni*16 + lx;
                    int hk = (c >> 7) & 3;
                    int dd = c & 127;
                    int ii = dd >> 1;
#pragma unroll
                    for (int j = 0; j < 4; j++){
                        int r = r0 + j;
                        int bb2 = r >> 11, tt = r & 2047;
                        float v = acc[mi][ni][j];
                        float p = __shfl_xor(v, 1);
                        float2 cs = tab[tt * 64 + ii];
                        float o = (lx & 1) ? (v * cs.x + p * cs.y) : (v * cs.x - p * cs.y);
                        size_t tb = ((size_t)(bb2 * 4 + hk) * 32 + (tt >> 6)) * 8192;
                        u32 byte = (u32)((tt & 63) * 256) + (((u32)(2 * dd)) ^ ((u32)((tt & 7) << 4)));
                        Ktl[tb + byte / 2] = f2bf(o);
                    }
                }
        } else {
            // V: tiled transposed, sigma-permuted rows (sig(s) = (s&15)*4 + (s>>4)&3),
            // swizzled byte^=(d&7)<<4 — matches attn's P sigma-column layout.
#pragma unroll
            for (int mi = 0; mi < 8; mi++){
                int r0 = m0 + wm*128 + mi*16 + tg*4;
                int bb2 = r0 >> 11, ss = r0 & 2047;
                int sb = ss & 63;
#pragma unroll
                for (int ni = 0; ni < 4; ni++){
                    int c  = n0 + wn*64 + ni*16 + lx;
                    int hk = (c >> 7) & 3;
                    int d  = c & 127;
                    size_t tb = ((size_t)(bb2 * 4 + hk) * 32 + (ss >> 6)) * 8192;
                    u32 swzd = (u32)((d & 7) << 4);
#pragma unroll
                    for (int j = 0; j < 4; j++){
                        int s = sb + j;
                        int sig = ((s & 15) << 2) | ((s >> 4) & 3);
                        u32 byte = (u32)(d * 128) + (((u32)(2 * sig)) ^ swzd);
                        Vtl[tb + byte / 2] = f2bf(acc[mi][ni][j]);
                    }
                }
            }
        }
    }
}

// ---------------- causal GQA flash attention (unchanged from R6) ----------------
// Q: plain (b*T+t, h*128+d) bf16, PRE-SCALED by scale*log2e (exp2 domain)
// Kt: [b][hkv][t32][s64][d128] swizzled (byte^=(s&7)<<4)
// Vt: [b][hkv][t32][d128][sig64] sigma-permuted, swizzled (byte^=(d&7)<<4)
__global__ __launch_bounds__(256) void attn5(const u16* __restrict__ Q, const u16* __restrict__ Kt,
                                             const u16* __restrict__ Vt, u16* __restrict__ Y){
    __shared__ __attribute__((aligned(16))) u16 Ks[2][64 * 128];
    __shared__ __attribute__((aligned(16))) u16 Vs[2][64 * 128];
    __shared__ __attribute__((aligned(16))) u16 Pl[4][16 * 64];
    const int lane = threadIdx.x & 63, w = threadIdx.x >> 6;
    const int jb = blockIdx.x, h = blockIdx.y, b = blockIdx.z;
    const int hkv = h >> 2;
    const size_t kvBase = ((size_t)(b * NKV + hkv) * 32) * 8192;
    const f32x4 Z = {0.f, 0.f, 0.f, 0.f};
    const int tg = lane >> 4, lx = lane & 15;

    auto STAGE = [&](int buf, int it){
        const u16* kg = Kt + kvBase + (size_t)it * 8192;
        const u16* vg = Vt + kvBase + (size_t)it * 8192;
#pragma unroll
        for (int i = 0; i < 4; i++){
            int is = w * 4 + i;
            gld_lds16(kg + is * 512 + lane * 8, &Ks[buf][is * 512]);
            gld_lds16(vg + is * 512 + lane * 8, &Vs[buf][is * 512]);
        }
    };

#pragma unroll 1
    for (int pass = 0; pass < 2; pass++){
        const int qt = pass == 0 ? jb : 31 - jb;
        const int q0 = qt * 64;
        const int qrow = q0 + w * 16 + lx;
        bf16x8 qfr[4];
#pragma unroll
        for (int kk = 0; kk < 4; kk++)
            qfr[kk] = *(const bf16x8*)(Q + (size_t)(b * T_ + qrow) * DM + h * HD + kk * 32 + tg * 8);
        f32x4 accO[8];
#pragma unroll
        for (int i = 0; i < 8; i++) accO[i] = Z;
        float mr[4] = {-INFINITY, -INFINITY, -INFINITY, -INFINITY};
        float lp[4] = {0.f, 0.f, 0.f, 0.f};
        const int nIter = qt + 1;

        STAGE(0, 0);
        __syncthreads();
        int cur = 0;

#pragma unroll 1
        for (int it = 0; it < nIter; it++){
            if (it + 1 < nIter) STAGE(cur ^ 1, it + 1);
            f32x4 sa[4];
#pragma unroll
            for (int c = 0; c < 4; c++) sa[c] = Z;
            __builtin_amdgcn_s_setprio(1);
#pragma unroll
            for (int c = 0; c < 4; c++){
                int s = c * 16 + lx;
                u32 swz = (u32)((s & 7) << 4);
                const char* kb = (const char*)&Ks[cur][0] + s * 256;
#pragma unroll
                for (int kk = 0; kk < 4; kk++){
                    bf16x8 kf = *(const bf16x8*)(kb + (((u32)(kk * 64 + tg * 16)) ^ swz));
                    sa[c] = __builtin_amdgcn_mfma_f32_16x16x32_bf16(qfr[kk], kf, sa[c], 0, 0, 0);
                }
            }
            __builtin_amdgcn_s_setprio(0);
            const bool diag = (it == nIter - 1);
            float tl[4];
#pragma unroll
            for (int j = 0; j < 4; j++){
                float a0 = sa[0][j], a1 = sa[1][j], a2 = sa[2][j], a3 = sa[3][j];
                if (diag){
                    int qloc = w * 16 + tg * 4 + j;
                    if (lx      > qloc) a0 = -INFINITY;
                    if (lx + 16 > qloc) a1 = -INFINITY;
                    if (lx + 32 > qloc) a2 = -INFINITY;
                    if (lx + 48 > qloc) a3 = -INFINITY;
                }
                sa[0][j] = a0; sa[1][j] = a1; sa[2][j] = a2; sa[3][j] = a3;
                tl[j] = fmaxf(fmaxf(a0, a1), fmaxf(a2, a3));
            }
            int lok = (tl[0] <= mr[0] + 8.f) && (tl[1] <= mr[1] + 8.f) &&
                      (tl[2] <= mr[2] + 8.f) && (tl[3] <= mr[3] + 8.f);
            if (!__all(lok)){
                float corr[4];
#pragma unroll
                for (int j = 0; j < 4; j++){
                    float t = tl[j];
                    t = fmaxf(t, __shfl_xor(t, 1));
                    t = fmaxf(t, __shfl_xor(t, 2));
                    t = fmaxf(t, __shfl_xor(t, 4));
                    t = fmaxf(t, __shfl_xor(t, 8));
                    float mn = fmaxf(mr[j], t);
                    corr[j] = ex2(mr[j] - mn);
                    mr[j] = mn;
                    lp[j] *= corr[j];
                }
#pragma unroll
                for (int dt = 0; dt < 8; dt++){
                    f32x4 t = accO[dt];
                    t[0] *= corr[0]; t[1] *= corr[1]; t[2] *= corr[2]; t[3] *= corr[3];
                    accO[dt] = t;
                }
            }
#pragma unroll
            for (int j = 0; j < 4; j++){
                float mn = mr[j];
                float p0 = ex2(sa[0][j] - mn), p1 = ex2(sa[1][j] - mn);
                float p2 = ex2(sa[2][j] - mn), p3 = ex2(sa[3][j] - mn);
                lp[j] += p0 + p1 + p2 + p3;
                int rr = tg * 4 + j;
                u32 woff = (u32)(rr * 128) + (((u32)(lx * 8)) ^ ((u32)((rr & 7) << 4)));
                u32 r01, r23;
                asm("v_cvt_pk_bf16_f32 %0, %1, %2" : "=v"(r01) : "v"(p0), "v"(p1));
                asm("v_cvt_pk_bf16_f32 %0, %1, %2" : "=v"(r23) : "v"(p2), "v"(p3));
                uint2 pk2 = make_uint2(r01, r23);
                *(uint2*)((char*)&Pl[w][0] + woff) = pk2;
            }
            bf16x8 pf[2];
            {
                char* pb = (char*)&Pl[w][0] + lx * 128;
                u32 swz = (u32)((lx & 7) << 4);
                pf[0] = *(const bf16x8*)(pb + (((u32)(tg * 16))      ^ swz));
                pf[1] = *(const bf16x8*)(pb + (((u32)(tg * 16 + 64)) ^ swz));
            }
            __builtin_amdgcn_s_setprio(1);
#pragma unroll
            for (int dt = 0; dt < 8; dt++){
                int d = dt * 16 + lx;
                u32 swz = (u32)((d & 7) << 4);
                const char* vb = (const char*)&Vs[cur][0] + d * 128;
                bf16x8 vf0 = *(const bf16x8*)(vb + (((u32)(tg * 16))      ^ swz));
                bf16x8 vf1 = *(const bf16x8*)(vb + (((u32)(tg * 16 + 64)) ^ swz));
                accO[dt] = __builtin_amdgcn_mfma_f32_16x16x32_bf16(pf[0], vf0, accO[dt], 0, 0, 0);
                accO[dt] = __builtin_amdgcn_mfma_f32_16x16x32_bf16(pf[1], vf1, accO[dt], 0, 0, 0);
            }
            __builtin_amdgcn_s_setprio(0);
            __syncthreads();
            cur ^= 1;
        }
        float inv[4];
#pragma unroll
        for (int j = 0; j < 4; j++){
            float s = lp[j];
            s += __shfl_xor(s, 1);
            s += __shfl_xor(s, 2);
            s += __shfl_xor(s, 4);
            s += __shfl_xor(s, 8);
            inv[j] = 1.0f / s;
        }
#pragma unroll
        for (int dt = 0; dt < 8; dt++)
#pragma unroll
            for (int j = 0; j < 4; j++){
                int qr = q0 + w * 16 + tg * 4 + j;
                int d = dt * 16 + lx;
                Y[(size_t)(b * T_ + qr) * DM + h * HD + d] = f2bf(accO[dt][j] * inv[j]);
            }
    }
}

extern "C" void kernel_launch(void* const* d_in, const int* in_sizes, int n_in,
                              void* d_out, int out_size, void* d_ws, size_t ws_size,
                              hipStream_t stream){
    const float* x  = (const float*)d_in[0];
    const float* Wq = (const float*)d_in[1];
    const float* Wk = (const float*)d_in[2];
    const float* Wv = (const float*)d_in[3];
    const float* Wo = (const float*)d_in[4];

    char* ws = (char*)d_ws;
    size_t off = 0;
    auto alloc = [&](size_t bytes){ void* p = ws + off; off += (bytes + 255) & ~255ull; return p; };
    u16*    xb   = (u16*)alloc(4096ull * 2048 * 2);
    u16*    Wqkv = (u16*)alloc(3072ull * 2048 * 2);
    u16*    Wot  = (u16*)alloc(2048ull * 2048 * 2);
    u16*    qbb  = (u16*)alloc(4096ull * 2048 * 2);
    u16*    ktl  = (u16*)alloc(2ull * 4 * 32 * 8192 * 2);
    u16*    vtl  = (u16*)alloc(2ull * 4 * 32 * 8192 * 2);
    u16*    ybb  = (u16*)alloc(4096ull * 2048 * 2);
    float2* tab  = (float2*)alloc(2048ull * 64 * 8);

    prep<<<18944, 256, 0, stream>>>(x, Wq, Wk, Wv, Wo, xb, Wqkv, Wot, tab);

    gemm256<1><<<192, 512, 0, stream>>>(xb, Wqkv, qbb, ktl, vtl, tab, 12);

    attn5<<<dim3(16, 16, 2), 256, 0, stream>>>(qbb, ktl, vtl, ybb);

    gemm256<0><<<128, 512, 0, stream>>>(ybb, Wot, d_out, nullptr, nullptr, nullptr, 8);
}

// Round 9
// 203.479 us; speedup vs baseline: 1.1169x; 1.0734x over previous
//
#include <hip/hip_runtime.h>
#include <hip/hip_bf16.h>

typedef unsigned short u16;
typedef unsigned int u32;
typedef __attribute__((ext_vector_type(4))) float f32x4;
typedef __attribute__((ext_vector_type(8))) __bf16 bf16x8;

#define B_   2
#define T_   2048
#define DM   2048
#define NH   16
#define NKV  4
#define HD   128

__device__ __forceinline__ u16 f2bf(float f){
    u32 u = __builtin_bit_cast(u32, f);
    u += 0x7FFFu + ((u >> 16) & 1u);
    return (u16)(u >> 16);
}
__device__ __forceinline__ float bf2f(u16 v){
    return __builtin_bit_cast(float, (u32)v << 16);
}

__device__ __forceinline__ float ex2(float x){
    float r; asm("v_exp_f32 %0, %1" : "=v"(r) : "v"(x)); return r;
}

__device__ __forceinline__ void gld_lds16(const void* g, void* l){
    __builtin_amdgcn_global_load_lds(
        (const __attribute__((address_space(1))) void*)g,
        (__attribute__((address_space(3))) void*)l, 16, 0, 0);
}

// ---------------- fused prep: cast x, transpose weights, rope table ----------------
__global__ void prep(const float* __restrict__ x,
                     const float* __restrict__ Wq, const float* __restrict__ Wk,
                     const float* __restrict__ Wv, const float* __restrict__ Wo,
                     u16* __restrict__ xb, u16* __restrict__ Wqkv, u16* __restrict__ Wot,
                     float2* __restrict__ tab){
    __shared__ float tile[32][33];
    int bid = blockIdx.x, tid = threadIdx.x;
    if (bid < 8192){
        int i = bid * 256 + tid;
        float4 v = ((const float4*)x)[i];
        ushort4 o;
        o.x = f2bf(v.x); o.y = f2bf(v.y); o.z = f2bf(v.z); o.w = f2bf(v.w);
        ((ushort4*)xb)[i] = o;
    } else if (bid < 18432){
        int tb = bid - 8192;
        int bx = tb % 160, byy = tb / 160;
        const float* W; u16* Out; int N; int nb; int perm;
        if (bx < 64)      { W = Wq; Out = Wqkv;                  N = 2048; nb = bx;      perm = 1; }
        else if (bx < 80) { W = Wk; Out = Wqkv + 2048ull * 2048; N = 512;  nb = bx - 64; perm = 1; }
        else if (bx < 96) { W = Wv; Out = Wqkv + 2560ull * 2048; N = 512;  nb = bx - 80; perm = 0; }
        else              { W = Wo; Out = Wot;                   N = 2048; nb = bx - 96; perm = 0; }
        int n0 = nb * 32, k0 = byy * 32;
        int tx = tid & 31, ty = tid >> 5;
#pragma unroll
        for (int i = 0; i < 4; i++)
            tile[ty + i * 8][tx] = W[(size_t)(k0 + ty + i * 8) * N + n0 + tx];
        __syncthreads();
#pragma unroll
        for (int i = 0; i < 4; i++){
            int n = n0 + ty + i * 8;
            int np = perm ? ((n & ~127) | ((n & 63) << 1) | ((n >> 6) & 1)) : n;
            Out[(size_t)np * 2048 + k0 + tx] = f2bf(tile[tx][ty + i * 8]);
        }
    } else {
        int idx = (bid - 18432) * 256 + tid;
        int i = idx & 63, t = idx >> 6;
        float ang = (float)t * exp2f((float)i * (-13.287712379549449f / 64.0f));
        float sv, cv;
        __sincosf(ang, &sv, &cv);
        tab[idx] = make_float2(cv, sv);
    }
}

// ================= 256x256 8-phase GEMM (depinned; T2+T3+T4+T5) =================
// MODE 1: QKV (grid 192, NIT=16): routes Q+rope / K+rope->Kt / V->Vt.
// MODE 2: Wo split-K (grid 256 = 128 tiles x 2 K-halves, NIT=8): bf16 partials.
// Barriers are raw s_barrier (compiler memory fence only); NO manual lgkmcnt /
// sched_barrier — compiler emits counted per-wave waits (m97 evidence), waves
// destagger, setprio arbitrates MFMA. VM4 at c3/c7 retires dead-region stages.
#define BARR() asm volatile("s_barrier" ::: "memory")
#define VM4()  asm volatile("s_waitcnt vmcnt(4)" ::: "memory")
#define VM8()  asm volatile("s_waitcnt vmcnt(8)" ::: "memory")

#define READ_A(QA, BUF) { \
    const char* ab = (const char*)&As[BUF][wm][0]; \
    _Pragma("unroll") for (int i = 0; i < 4; i++){ \
        int rh = ((QA)*4 + i)*16 + lx; \
        _Pragma("unroll") for (int ks = 0; ks < 2; ks++) \
            a_[i][ks] = *(const bf16x8*)(ab + rh*128 + (((ks*4+tg)*16) ^ ((lx&7)<<4))); \
    } }
#define READ_B(QB, BUF) { \
    const char* bb = (const char*)&Bs[BUF][wn>>1][0]; \
    _Pragma("unroll") for (int n = 0; n < 2; n++){ \
        int rbh = (wn&1)*64 + ((QB)*2+n)*16 + lx; \
        _Pragma("unroll") for (int ks = 0; ks < 2; ks++) \
            b_[(QB)*2+n][ks] = *(const bf16x8*)(bb + rbh*128 + (((ks*4+tg)*16) ^ ((lx&7)<<4))); \
    } }
#define MFMA_Q(QA, QB) { \
    __builtin_amdgcn_s_setprio(1); \
    _Pragma("unroll") for (int i = 0; i < 4; i++) \
    _Pragma("unroll") for (int n = 0; n < 2; n++) \
    _Pragma("unroll") for (int ks = 0; ks < 2; ks++) \
        acc[(QA)*4+i][(QB)*2+n] = __builtin_amdgcn_mfma_f32_16x16x32_bf16( \
            a_[i][ks], b_[(QB)*2+n][ks], acc[(QA)*4+i][(QB)*2+n], 0, 0, 0); \
    __builtin_amdgcn_s_setprio(0); }

template<int MODE>
__global__ __launch_bounds__(512, 2) void gemm256(const u16* __restrict__ A, const u16* __restrict__ Bt,
                                                  void* __restrict__ O0, u16* __restrict__ Ktl,
                                                  u16* __restrict__ Vtl, const float2* __restrict__ tab,
                                                  int NBX){
    __shared__ __attribute__((aligned(16))) u16 As[2][2][8192];
    __shared__ __attribute__((aligned(16))) u16 Bs[2][2][8192];
    const int tid = threadIdx.x;
    const int lane = tid & 63, w = tid >> 6;
    const int wm = w >> 2, wn = w & 3;
    const int tg = lane >> 4, lx = lane & 15;
    int q8 = (int)gridDim.x >> 3;
    int swz = ((int)blockIdx.x & 7) * q8 + ((int)blockIdx.x >> 3);
    int kh = 0;
    if constexpr (MODE == 2){ kh = swz >> 7; swz &= 127; }
    const int bx = swz % NBX, by = swz / NBX;
    const int m0 = by * 256, n0 = bx * 256;
    const int K = 2048;
    const int NIT = (MODE == 2) ? 8 : 16;
    const int kt0 = kh * 16;
    const int ltMax = 2 * NIT - 1;
    const int kcx = (lane & 7) ^ ((lane >> 3) & 7);

    f32x4 acc[8][4];
    const f32x4 Z = {0.f, 0.f, 0.f, 0.f};
#pragma unroll
    for (int i = 0; i < 8; i++)
#pragma unroll
        for (int j = 0; j < 4; j++) acc[i][j] = Z;
    bf16x8 a_[4][2], b_[4][2];

    auto stA = [&](int buf, int q, int kt){
        int mh = w >> 2;
        int s0 = (w & 3) * 2;
#pragma unroll
        for (int l = 0; l < 2; l++){
            int s = s0 + l;
            gld_lds16(A + (size_t)(m0 + mh*128 + q*64 + s*8 + (lane>>3)) * K + kt*64 + kcx*8,
                      &As[buf][mh][q*4096 + s*512 + lane*8]);
        }
    };
    auto stB = [&](int buf, int q, int kt){
        int bh = w >> 2;
        int hi = (w >> 1) & 1;
        int s0 = (w & 1) * 2;
#pragma unroll
        for (int l = 0; l < 2; l++){
            int s = s0 + l;
            gld_lds16(Bt + (size_t)(n0 + bh*128 + hi*64 + q*32 + s*8 + (lane>>3)) * K + kt*64 + kcx*8,
                      &Bs[buf][bh][hi*4096 + q*2048 + s*512 + lane*8]);
        }
    };

    // prologue: T0 full, T1 regions A0/B0
    stA(0, 0, kt0); stB(0, 0, kt0); stA(0, 1, kt0); stB(0, 1, kt0);
    stA(1, 0, kt0 + 1); stB(1, 0, kt0 + 1);
    VM4(); BARR();

#pragma unroll 1
    for (int it = 0; it < NIT; it++){
        const int T1 = kt0 + 2*it + 1;
        const int T2 = kt0 + ((2*it + 2 < ltMax) ? 2*it + 2 : ltMax);
        const int T3 = kt0 + ((2*it + 3 < ltMax) ? 2*it + 3 : ltMax);
        // c0: buf0 quadrant (0,0)
        READ_A(0, 0); READ_B(0, 0); stA(1, 1, T1);
        BARR(); MFMA_Q(0, 0); BARR();
        // c1: (0,1)
        READ_B(1, 0); stB(1, 1, T1);
        BARR(); MFMA_Q(0, 1); BARR();
        // c2: (1,0)
        READ_A(1, 0); stA(0, 0, T2);
        BARR(); MFMA_Q(1, 0); BARR();
        // c3: (1,1) + counted vmcnt
        stB(0, 0, T2);
        BARR(); MFMA_Q(1, 1); VM4(); BARR();
        // c4: buf1 quadrant (0,0)
        READ_A(0, 1); READ_B(0, 1); stA(0, 1, T2);
        BARR(); MFMA_Q(0, 0); BARR();
        // c5: (0,1)
        READ_B(1, 1); stB(0, 1, T2);
        BARR(); MFMA_Q(0, 1); BARR();
        // c6: (1,0)
        READ_A(1, 1); stA(1, 0, T3);
        BARR(); MFMA_Q(1, 0); BARR();
        // c7: (1,1) + counted vmcnt
        stB(1, 0, T3);
        BARR(); MFMA_Q(1, 1); VM4(); BARR();
    }

    // ---------------- epilogue ----------------
    if constexpr (MODE == 2){
        // bf16 partial, buffer kh
        u16* C = (u16*)O0 + (size_t)kh * 4096 * 2048;
#pragma unroll
        for (int mi = 0; mi < 8; mi++)
#pragma unroll
            for (int ni = 0; ni < 4; ni++){
                int r0 = m0 + wm*128 + mi*16 + tg*4;
                int c  = n0 + wn*64 + ni*16 + lx;
#pragma unroll
                for (int j = 0; j < 4; j++)
                    C[(size_t)(r0 + j) * 2048 + c] = f2bf(acc[mi][ni][j]);
            }
    } else {
        u16* Qp = (u16*)O0;
        if (bx < 8){
            const float QS = 0.08838834764831845f * 1.4426950408889634f;
#pragma unroll
            for (int mi = 0; mi < 8; mi++)
#pragma unroll
                for (int ni = 0; ni < 4; ni++){
                    int r0 = m0 + wm*128 + mi*16 + tg*4;
                    int c  = n0 + wn*64 + ni*16 + lx;
                    int ii = (c & 127) >> 1;
#pragma unroll
                    for (int j = 0; j < 4; j++){
                        float v = acc[mi][ni][j];
                        float p = __shfl_xor(v, 1);
                        int t = (r0 + j) & 2047;
                        float2 cs = tab[t * 64 + ii];
                        float o = ((lx & 1) ? (v * cs.x + p * cs.y) : (v * cs.x - p * cs.y)) * QS;
                        Qp[(size_t)(r0 + j) * 2048 + c] = f2bf(o);
                    }
                }
        } else if (bx < 10){
#pragma unroll
            for (int mi = 0; mi < 8; mi++)
#pragma unroll
                for (int ni = 0; ni < 4; ni++){
                    int r0 = m0 + wm*128 + mi*16 + tg*4;
                    int c  = n0 + wn*64 + ni*16 + lx;
                    int hk = (c >> 7) & 3;
                    int dd = c & 127;
                    int ii = dd >> 1;
#pragma unroll
                    for (int j = 0; j < 4; j++){
                        int r = r0 + j;
                        int bb2 = r >> 11, tt = r & 2047;
                        float v = acc[mi][ni][j];
                        float p = __shfl_xor(v, 1);
                        float2 cs = tab[tt * 64 + ii];
                        float o = (lx & 1) ? (v * cs.x + p * cs.y) : (v * cs.x - p * cs.y);
                        size_t tb = ((size_t)(bb2 * 4 + hk) * 32 + (tt >> 6)) * 8192;
                        u32 byte = (u32)((tt & 63) * 256) + (((u32)(2 * dd)) ^ ((u32)((tt & 7) << 4)));
                        Ktl[tb + byte / 2] = f2bf(o);
                    }
                }
        } else {
#pragma unroll
            for (int mi = 0; mi < 8; mi++){
                int r0 = m0 + wm*128 + mi*16 + tg*4;
                int bb2 = r0 >> 11, ss = r0 & 2047;
                int sb = ss & 63;
#pragma unroll
                for (int ni = 0; ni < 4; ni++){
                    int c  = n0 + wn*64 + ni*16 + lx;
                    int hk = (c >> 7) & 3;
                    int d  = c & 127;
                    size_t tb = ((size_t)(bb2 * 4 + hk) * 32 + (ss >> 6)) * 8192;
                    u32 swzd = (u32)((d & 7) << 4);
#pragma unroll
                    for (int j = 0; j < 4; j++){
                        int s = sb + j;
                        int sig = ((s & 15) << 2) | ((s >> 4) & 3);
                        u32 byte = (u32)(d * 128) + (((u32)(2 * sig)) ^ swzd);
                        Vtl[tb + byte / 2] = f2bf(acc[mi][ni][j]);
                    }
                }
            }
        }
    }
}

// ---------------- split-K reduce: d_out = bf16(P0) + bf16(P1), f32 out ----------------
__global__ void reduceWo(const u16* __restrict__ P, float* __restrict__ out){
    size_t t = (size_t)blockIdx.x * 256 + threadIdx.x;  // 8 elems each
    const u16* p0 = P + t * 8;
    const u16* p1 = P + 4096ull * 2048 + t * 8;
    uint4 a = *(const uint4*)p0;
    uint4 b = *(const uint4*)p1;
    const u16* as = (const u16*)&a;
    const u16* bs = (const u16*)&b;
    float4 o0, o1;
    o0.x = bf2f(as[0]) + bf2f(bs[0]); o0.y = bf2f(as[1]) + bf2f(bs[1]);
    o0.z = bf2f(as[2]) + bf2f(bs[2]); o0.w = bf2f(as[3]) + bf2f(bs[3]);
    o1.x = bf2f(as[4]) + bf2f(bs[4]); o1.y = bf2f(as[5]) + bf2f(bs[5]);
    o1.z = bf2f(as[6]) + bf2f(bs[6]); o1.w = bf2f(as[7]) + bf2f(bs[7]);
    ((float4*)out)[t * 2]     = o0;
    ((float4*)out)[t * 2 + 1] = o1;
}

// ---------------- causal GQA flash attention (unchanged) ----------------
__global__ __launch_bounds__(256) void attn5(const u16* __restrict__ Q, const u16* __restrict__ Kt,
                                             const u16* __restrict__ Vt, u16* __restrict__ Y){
    __shared__ __attribute__((aligned(16))) u16 Ks[2][64 * 128];
    __shared__ __attribute__((aligned(16))) u16 Vs[2][64 * 128];
    __shared__ __attribute__((aligned(16))) u16 Pl[4][16 * 64];
    const int lane = threadIdx.x & 63, w = threadIdx.x >> 6;
    const int jb = blockIdx.x, h = blockIdx.y, b = blockIdx.z;
    const int hkv = h >> 2;
    const size_t kvBase = ((size_t)(b * NKV + hkv) * 32) * 8192;
    const f32x4 Z = {0.f, 0.f, 0.f, 0.f};
    const int tg = lane >> 4, lx = lane & 15;

    auto STAGE = [&](int buf, int it){
        const u16* kg = Kt + kvBase + (size_t)it * 8192;
        const u16* vg = Vt + kvBase + (size_t)it * 8192;
#pragma unroll
        for (int i = 0; i < 4; i++){
            int is = w * 4 + i;
            gld_lds16(kg + is * 512 + lane * 8, &Ks[buf][is * 512]);
            gld_lds16(vg + is * 512 + lane * 8, &Vs[buf][is * 512]);
        }
    };

#pragma unroll 1
    for (int pass = 0; pass < 2; pass++){
        const int qt = pass == 0 ? jb : 31 - jb;
        const int q0 = qt * 64;
        const int qrow = q0 + w * 16 + lx;
        bf16x8 qfr[4];
#pragma unroll
        for (int kk = 0; kk < 4; kk++)
            qfr[kk] = *(const bf16x8*)(Q + (size_t)(b * T_ + qrow) * DM + h * HD + kk * 32 + tg * 8);
        f32x4 accO[8];
#pragma unroll
        for (int i = 0; i < 8; i++) accO[i] = Z;
        float mr[4] = {-INFINITY, -INFINITY, -INFINITY, -INFINITY};
        float lp[4] = {0.f, 0.f, 0.f, 0.f};
        const int nIter = qt + 1;

        STAGE(0, 0);
        __syncthreads();
        int cur = 0;

#pragma unroll 1
        for (int it = 0; it < nIter; it++){
            if (it + 1 < nIter) STAGE(cur ^ 1, it + 1);
            f32x4 sa[4];
#pragma unroll
            for (int c = 0; c < 4; c++) sa[c] = Z;
            __builtin_amdgcn_s_setprio(1);
#pragma unroll
            for (int c = 0; c < 4; c++){
                int s = c * 16 + lx;
                u32 swz = (u32)((s & 7) << 4);
                const char* kb = (const char*)&Ks[cur][0] + s * 256;
#pragma unroll
                for (int kk = 0; kk < 4; kk++){
                    bf16x8 kf = *(const bf16x8*)(kb + (((u32)(kk * 64 + tg * 16)) ^ swz));
                    sa[c] = __builtin_amdgcn_mfma_f32_16x16x32_bf16(qfr[kk], kf, sa[c], 0, 0, 0);
                }
            }
            __builtin_amdgcn_s_setprio(0);
            const bool diag = (it == nIter - 1);
            float tl[4];
#pragma unroll
            for (int j = 0; j < 4; j++){
                float a0 = sa[0][j], a1 = sa[1][j], a2 = sa[2][j], a3 = sa[3][j];
                if (diag){
                    int qloc = w * 16 + tg * 4 + j;
                    if (lx      > qloc) a0 = -INFINITY;
                    if (lx + 16 > qloc) a1 = -INFINITY;
                    if (lx + 32 > qloc) a2 = -INFINITY;
                    if (lx + 48 > qloc) a3 = -INFINITY;
                }
                sa[0][j] = a0; sa[1][j] = a1; sa[2][j] = a2; sa[3][j] = a3;
                tl[j] = fmaxf(fmaxf(a0, a1), fmaxf(a2, a3));
            }
            int lok = (tl[0] <= mr[0] + 8.f) && (tl[1] <= mr[1] + 8.f) &&
                      (tl[2] <= mr[2] + 8.f) && (tl[3] <= mr[3] + 8.f);
            if (!__all(lok)){
                float corr[4];
#pragma unroll
                for (int j = 0; j < 4; j++){
                    float t = tl[j];
                    t = fmaxf(t, __shfl_xor(t, 1));
                    t = fmaxf(t, __shfl_xor(t, 2));
                    t = fmaxf(t, __shfl_xor(t, 4));
                    t = fmaxf(t, __shfl_xor(t, 8));
                    float mn = fmaxf(mr[j], t);
                    corr[j] = ex2(mr[j] - mn);
                    mr[j] = mn;
                    lp[j] *= corr[j];
                }
#pragma unroll
                for (int dt = 0; dt < 8; dt++){
                    f32x4 t = accO[dt];
                    t[0] *= corr[0]; t[1] *= corr[1]; t[2] *= corr[2]; t[3] *= corr[3];
                    accO[dt] = t;
                }
            }
#pragma unroll
            for (int j = 0; j < 4; j++){
                float mn = mr[j];
                float p0 = ex2(sa[0][j] - mn), p1 = ex2(sa[1][j] - mn);
                float p2 = ex2(sa[2][j] - mn), p3 = ex2(sa[3][j] - mn);
                lp[j] += p0 + p1 + p2 + p3;
                int rr = tg * 4 + j;
                u32 woff = (u32)(rr * 128) + (((u32)(lx * 8)) ^ ((u32)((rr & 7) << 4)));
                u32 r01, r23;
                asm("v_cvt_pk_bf16_f32 %0, %1, %2" : "=v"(r01) : "v"(p0), "v"(p1));
                asm("v_cvt_pk_bf16_f32 %0, %1, %2" : "=v"(r23) : "v"(p2), "v"(p3));
                uint2 pk2 = make_uint2(r01, r23);
                *(uint2*)((char*)&Pl[w][0] + woff) = pk2;
            }
            bf16x8 pf[2];
            {
                char* pb = (char*)&Pl[w][0] + lx * 128;
                u32 swz = (u32)((lx & 7) << 4);
                pf[0] = *(const bf16x8*)(pb + (((u32)(tg * 16))      ^ swz));
                pf[1] = *(const bf16x8*)(pb + (((u32)(tg * 16 + 64)) ^ swz));
            }
            __builtin_amdgcn_s_setprio(1);
#pragma unroll
            for (int dt = 0; dt < 8; dt++){
                int d = dt * 16 + lx;
                u32 swz = (u32)((d & 7) << 4);
                const char* vb = (const char*)&Vs[cur][0] + d * 128;
                bf16x8 vf0 = *(const bf16x8*)(vb + (((u32)(tg * 16))      ^ swz));
                bf16x8 vf1 = *(const bf16x8*)(vb + (((u32)(tg * 16 + 64)) ^ swz));
                accO[dt] = __builtin_amdgcn_mfma_f32_16x16x32_bf16(pf[0], vf0, accO[dt], 0, 0, 0);
                accO[dt] = __builtin_amdgcn_mfma_f32_16x16x32_bf16(pf[1], vf1, accO[dt], 0, 0, 0);
            }
            __builtin_amdgcn_s_setprio(0);
            __syncthreads();
            cur ^= 1;
        }
        float inv[4];
#pragma unroll
        for (int j = 0; j < 4; j++){
            float s = lp[j];
            s += __shfl_xor(s, 1);
            s += __shfl_xor(s, 2);
            s += __shfl_xor(s, 4);
            s += __shfl_xor(s, 8);
            inv[j] = 1.0f / s;
        }
#pragma unroll
        for (int dt = 0; dt < 8; dt++)
#pragma unroll
            for (int j = 0; j < 4; j++){
                int qr = q0 + w * 16 + tg * 4 + j;
                int d = dt * 16 + lx;
                Y[(size_t)(b * T_ + qr) * DM + h * HD + d] = f2bf(accO[dt][j] * inv[j]);
            }
    }
}

extern "C" void kernel_launch(void* const* d_in, const int* in_sizes, int n_in,
                              void* d_out, int out_size, void* d_ws, size_t ws_size,
                              hipStream_t stream){
    const float* x  = (const float*)d_in[0];
    const float* Wq = (const float*)d_in[1];
    const float* Wk = (const float*)d_in[2];
    const float* Wv = (const float*)d_in[3];
    const float* Wo = (const float*)d_in[4];

    char* ws = (char*)d_ws;
    size_t off = 0;
    auto alloc = [&](size_t bytes){ void* p = ws + off; off += (bytes + 255) & ~255ull; return p; };
    u16*    xb   = (u16*)alloc(4096ull * 2048 * 2);
    u16*    Wqkv = (u16*)alloc(3072ull * 2048 * 2);
    u16*    Wot  = (u16*)alloc(2048ull * 2048 * 2);
    u16*    qbb  = (u16*)alloc(4096ull * 2048 * 2);
    u16*    ktl  = (u16*)alloc(2ull * 4 * 32 * 8192 * 2);
    u16*    vtl  = (u16*)alloc(2ull * 4 * 32 * 8192 * 2);
    u16*    ybb  = (u16*)alloc(4096ull * 2048 * 2);
    u16*    pbb  = (u16*)alloc(2ull * 4096 * 2048 * 2);
    float2* tab  = (float2*)alloc(2048ull * 64 * 8);

    prep<<<18944, 256, 0, stream>>>(x, Wq, Wk, Wv, Wo, xb, Wqkv, Wot, tab);

    gemm256<1><<<192, 512, 0, stream>>>(xb, Wqkv, qbb, ktl, vtl, tab, 12);

    attn5<<<dim3(16, 16, 2), 256, 0, stream>>>(qbb, ktl, vtl, ybb);

    gemm256<2><<<256, 512, 0, stream>>>(ybb, Wot, pbb, nullptr, nullptr, nullptr, 8);
    reduceWo<<<4096, 256, 0, stream>>>(pbb, (float*)d_out);
}